// Round 1
// baseline (336.019 us; speedup 1.0000x reference)
//
#include <hip/hip_runtime.h>
#include <math.h>

#define N_NODES 20000
#define N_EDGES 320000
#define HIDDEN 64
#define HEADS 4
#define HC 256              // HEADS*HIDDEN
#define D_INNER 256
#define NEG_SLOPE 0.2f
#define BN_EPS 1e-5f

// ---- ordered-float encoding for atomicMax on float via uint ----
__device__ __forceinline__ unsigned ford(float f) {
    unsigned u = __float_as_uint(f);
    return (u & 0x80000000u) ? ~u : (u | 0x80000000u);
}
__device__ __forceinline__ float funord(unsigned e) {
    unsigned u = (e & 0x80000000u) ? (e ^ 0x80000000u) : ~e;
    return __uint_as_float(u);
}

// ---- K1: xl = x@W_l + b_l ; xr = x@W_r + b_r  (16 nodes / block) ----
__global__ __launch_bounds__(256) void k_lin(const float* __restrict__ x,
                                             const float* __restrict__ Wl, const float* __restrict__ bl,
                                             const float* __restrict__ Wr, const float* __restrict__ br,
                                             float* __restrict__ xl, float* __restrict__ xr) {
    __shared__ float sx[16][64];
    int t = threadIdx.x;
    int n0 = blockIdx.x * 16;
    for (int i = t; i < 16 * 64; i += 256) sx[i >> 6][i & 63] = x[n0 * 64 + i];
    __syncthreads();
    float accl[16], accr[16];
    float blv = bl[t], brv = br[t];
#pragma unroll
    for (int n = 0; n < 16; n++) { accl[n] = blv; accr[n] = brv; }
    for (int k = 0; k < 64; k++) {
        float wl = Wl[k * HC + t];
        float wr = Wr[k * HC + t];
#pragma unroll
        for (int n = 0; n < 16; n++) {
            accl[n] += sx[n][k] * wl;
            accr[n] += sx[n][k] * wr;
        }
    }
#pragma unroll
    for (int n = 0; n < 16; n++) {
        xl[(size_t)(n0 + n) * HC + t] = accl[n];
        xr[(size_t)(n0 + n) * HC + t] = accr[n];
    }
}

// ---- K2: per-edge attention score + segment max (1 wave / edge) ----
__global__ __launch_bounds__(256) void k_score(const float* __restrict__ xl, const float* __restrict__ xr,
                                               const float* __restrict__ att, const int* __restrict__ ei,
                                               float* __restrict__ score, unsigned* __restrict__ m_ord) {
    int e = blockIdx.x * 4 + (threadIdx.x >> 6);
    int lane = threadIdx.x & 63;
    int src = ei[e];
    int dst = ei[N_EDGES + e];
    float s[4];
#pragma unroll
    for (int h = 0; h < 4; h++) {
        float v = xl[(size_t)src * HC + h * 64 + lane] + xr[(size_t)dst * HC + h * 64 + lane];
        v = v >= 0.f ? v : NEG_SLOPE * v;
        s[h] = v * att[h * 64 + lane];
    }
#pragma unroll
    for (int off = 32; off > 0; off >>= 1) {
#pragma unroll
        for (int h = 0; h < 4; h++) s[h] += __shfl_xor(s[h], off);
    }
    if (lane == 0) {
#pragma unroll
        for (int h = 0; h < 4; h++) {
            score[e * 4 + h] = s[h];
            atomicMax(&m_ord[dst * 4 + h], ford(s[h]));
        }
    }
}

// ---- K3: ex = exp(score - m[dst]); denom += ex ----
__global__ __launch_bounds__(256) void k_exp(const float* __restrict__ score, const int* __restrict__ ei,
                                             const unsigned* __restrict__ m_ord,
                                             float* __restrict__ ex, float* __restrict__ denom) {
    int idx = blockIdx.x * 256 + threadIdx.x;     // E*4 total
    int e = idx >> 2, h = idx & 3;
    int dst = ei[N_EDGES + e];
    float m = funord(m_ord[dst * 4 + h]);
    float v = expf(score[idx] - m);
    ex[idx] = v;
    atomicAdd(&denom[dst * 4 + h], v);
}

// ---- K4: out_g[dst,c] += (1/H) * sum_h alpha[e,h]*xl[src,h,c]  (1 wave / edge) ----
__global__ __launch_bounds__(256) void k_gacc(const float* __restrict__ ex, const float* __restrict__ denom,
                                              const float* __restrict__ xl, const int* __restrict__ ei,
                                              float* __restrict__ out_g) {
    int e = blockIdx.x * 4 + (threadIdx.x >> 6);
    int lane = threadIdx.x & 63;
    int src = ei[e], dst = ei[N_EDGES + e];
    float acc = 0.f;
#pragma unroll
    for (int h = 0; h < 4; h++) {
        float al = ex[e * 4 + h] / fmaxf(denom[dst * 4 + h], 1e-16f);
        acc += al * xl[(size_t)src * HC + h * 64 + lane];
    }
    atomicAdd(&out_g[(size_t)dst * 64 + lane], 0.25f * acc);
}

// ---- K5: y1 = x + out_g + bias_gat ; accumulate BN1 sums ----
__global__ __launch_bounds__(256) void k_y1stats(const float* __restrict__ x, const float* __restrict__ out_g,
                                                 const float* __restrict__ bias,
                                                 float* __restrict__ y1,
                                                 float* __restrict__ gsum, float* __restrict__ gsq) {
    __shared__ float psum[4][64], psq[4][64];
    int t = threadIdx.x;
    int c = t & 63;
    float bv = bias[c];
    float s = 0.f, q = 0.f;
    for (int idx = blockIdx.x * 256 + t; idx < N_NODES * HIDDEN; idx += gridDim.x * 256) {
        float v = x[idx] + out_g[idx] + bv;
        y1[idx] = v;
        s += v; q += v * v;
    }
    psum[t >> 6][c] = s; psq[t >> 6][c] = q;
    __syncthreads();
    if (t < 64) {
        atomicAdd(&gsum[t], psum[0][t] + psum[1][t] + psum[2][t] + psum[3][t]);
        atomicAdd(&gsq[t], psq[0][t] + psq[1][t] + psq[2][t] + psq[3][t]);
    }
}

// ---- finalize BN scale/shift: a = gamma*rsqrt(var+eps); c = beta - mu*a ----
__global__ void k_bnfin(const float* __restrict__ gsum, const float* __restrict__ gsq,
                        const float* __restrict__ gamma, const float* __restrict__ beta,
                        float* __restrict__ a, float* __restrict__ c) {
    int t = threadIdx.x;   // 64 threads
    float mu = gsum[t] * (1.0f / N_NODES);
    float var = gsq[t] * (1.0f / N_NODES) - mu * mu;
    var = fmaxf(var, 0.f);
    float av = gamma[t] * rsqrtf(var + BN_EPS);
    a[t] = av;
    c[t] = beta[t] - mu * av;
}

// ---- K7: FFN (8 nodes / block): y = BN1(y1); out = y + relu(y@W1+b1)@W2+b2 ; BN2 sums ----
__global__ __launch_bounds__(256) void k_ffn(const float* __restrict__ y1,
                                             const float* __restrict__ a1, const float* __restrict__ c1,
                                             const float* __restrict__ W1, const float* __restrict__ b1,
                                             const float* __restrict__ W2, const float* __restrict__ b2,
                                             float* __restrict__ out,
                                             float* __restrict__ gsum, float* __restrict__ gsq) {
    __shared__ float sy[8][64];
    __shared__ float sh[8][256];
    __shared__ float psum[4][64], psq[4][64];
    int t = threadIdx.x;
    int n0 = blockIdx.x * 8;
    for (int i = t; i < 8 * 64; i += 256) {
        int c = i & 63;
        sy[i >> 6][c] = a1[c] * y1[(size_t)n0 * 64 + i] + c1[c];
    }
    __syncthreads();
    float acc[8];
    float bv = b1[t];
#pragma unroll
    for (int n = 0; n < 8; n++) acc[n] = bv;
    for (int k = 0; k < 64; k++) {
        float w = W1[k * D_INNER + t];
#pragma unroll
        for (int n = 0; n < 8; n++) acc[n] += sy[n][k] * w;
    }
#pragma unroll
    for (int n = 0; n < 8; n++) sh[n][t] = fmaxf(acc[n], 0.f);
    __syncthreads();
    float s = 0.f, q = 0.f;
    int c = t & 63;
#pragma unroll
    for (int rep = 0; rep < 2; rep++) {
        int n = (t >> 6) + rep * 4;
        float a2 = b2[c];
        for (int k = 0; k < 256; k++) a2 += sh[n][k] * W2[k * 64 + c];
        float v = sy[n][c] + a2;
        out[(size_t)(n0 + n) * 64 + c] = v;
        s += v; q += v * v;
    }
    psum[t >> 6][c] = s; psq[t >> 6][c] = q;
    __syncthreads();
    if (t < 64) {
        atomicAdd(&gsum[t], psum[0][t] + psum[1][t] + psum[2][t] + psum[3][t]);
        atomicAdd(&gsq[t], psq[0][t] + psq[1][t] + psq[2][t] + psq[3][t]);
    }
}

// ---- K9: apply BN2 in-place on out ----
__global__ __launch_bounds__(256) void k_apply(float* __restrict__ out,
                                               const float* __restrict__ a, const float* __restrict__ c) {
    int idx = blockIdx.x * 256 + threadIdx.x;
    int ch = idx & 63;
    out[idx] = a[ch] * out[idx] + c[ch];
}

extern "C" void kernel_launch(void* const* d_in, const int* in_sizes, int n_in,
                              void* d_out, int out_size, void* d_ws, size_t ws_size,
                              hipStream_t stream) {
    const float* x        = (const float*)d_in[0];
    const int*   ei       = (const int*)d_in[1];
    const float* Wl       = (const float*)d_in[2];
    const float* bl       = (const float*)d_in[3];
    const float* Wr       = (const float*)d_in[4];
    const float* br       = (const float*)d_in[5];
    const float* att      = (const float*)d_in[6];
    const float* bias_gat = (const float*)d_in[7];
    const float* gamma1   = (const float*)d_in[8];
    const float* beta1    = (const float*)d_in[9];
    const float* W1       = (const float*)d_in[10];
    const float* b1       = (const float*)d_in[11];
    const float* W2       = (const float*)d_in[12];
    const float* b2       = (const float*)d_in[13];
    const float* gamma2   = (const float*)d_in[14];
    const float* beta2    = (const float*)d_in[15];
    float* out = (float*)d_out;

    float* ws = (float*)d_ws;
    float*    xl    = ws;                                   // N*256
    float*    xr    = xl + (size_t)N_NODES * HC;            // N*256
    float*    score = xr + (size_t)N_NODES * HC;            // E*4
    float*    ex    = score + (size_t)N_EDGES * HEADS;      // E*4
    unsigned* m_ord = (unsigned*)(ex + (size_t)N_EDGES * HEADS); // N*4
    float*    denom = (float*)(m_ord + (size_t)N_NODES * HEADS); // N*4
    float*    out_g = denom + (size_t)N_NODES * HEADS;      // N*64
    float*    stats = out_g + (size_t)N_NODES * HIDDEN;     // 512: sum1,sq1,sum2,sq2,a1,c1,a2,c2
    float*    y1    = stats + 512;                          // N*64

    // zero all accumulators (m_ord..stats is contiguous)
    size_t zero_bytes = (size_t)((char*)(stats + 512) - (char*)m_ord);
    hipMemsetAsync(m_ord, 0, zero_bytes, stream);

    k_lin  <<<N_NODES / 16, 256, 0, stream>>>(x, Wl, bl, Wr, br, xl, xr);
    k_score<<<N_EDGES / 4, 256, 0, stream>>>(xl, xr, att, ei, score, m_ord);
    k_exp  <<<N_EDGES * HEADS / 256, 256, 0, stream>>>(score, ei, m_ord, ex, denom);
    k_gacc <<<N_EDGES / 4, 256, 0, stream>>>(ex, denom, xl, ei, out_g);
    k_y1stats<<<512, 256, 0, stream>>>(x, out_g, bias_gat, y1, stats + 0, stats + 64);
    k_bnfin<<<1, 64, 0, stream>>>(stats + 0, stats + 64, gamma1, beta1, stats + 256, stats + 320);
    k_ffn  <<<N_NODES / 8, 256, 0, stream>>>(y1, stats + 256, stats + 320, W1, b1, W2, b2, out,
                                             stats + 128, stats + 192);
    k_bnfin<<<1, 64, 0, stream>>>(stats + 128, stats + 192, gamma2, beta2, stats + 384, stats + 448);
    k_apply<<<N_NODES * HIDDEN / 256, 256, 0, stream>>>(out, stats + 384, stats + 448);
}